// Round 3
// baseline (1254.248 us; speedup 1.0000x reference)
//
#include <hip/hip_runtime.h>
#include <cstdint>

// Problem constants (from reference)
#define TSEQ 224
#define HID 128
#define G4 512              // 4*HID gates
#define NSEQ 1280           // BATCHES*SUB = 64*20
#define KTOT (TSEQ*HID)     // 28672
#define NT 16               // sequences per GEMM1 block
#define KSPLIT 8            // K-split for GEMM1
#define KCH 128             // K staging chunk
#define KPB (KTOT/KSPLIT)   // 3584

__device__ __forceinline__ float fast_sigmoid(float a) {
  float e = __expf(-a);
  return __builtin_amdgcn_rcpf(1.0f + e);
}
__device__ __forceinline__ float fast_tanh(float a) {
  float e = __expf(-2.0f * a);
  return fmaf(2.0f, __builtin_amdgcn_rcpf(1.0f + e), -1.0f);
}

// ---------------------------------------------------------------------------
// LSTM: one block per sequence, 512 threads, thread g owns gate g with W_hh
// row g in 128 VGPRs. R1 failed because the register allocator REMATERIALIZED
// the invariant W_hh loads into the t-loop (VGPR stayed 80, W_hh streamed
// from L1 at ~64B/cyc = the 868us wall). The empty asm below makes each
// weight the result of an opaque asm, not a load -> not rematerializable ->
// held resident. launch_bounds(512,2) keeps the VGPR cap at 256.
// ---------------------------------------------------------------------------
__global__ __launch_bounds__(512, 2) void lstm_kernel(
    const float* __restrict__ x,      // [NSEQ, TSEQ]
    const float* __restrict__ W_ih,   // [512, 1]
    const float* __restrict__ W_hh,   // [512, 128]
    const float* __restrict__ b_ih,   // [512]
    const float* __restrict__ b_hh,   // [512]
    float* __restrict__ hs)           // [NSEQ, TSEQ, HID]
{
  const int n = blockIdx.x;
  const int g = threadIdx.x;

  __shared__ float s_x[TSEQ];
  __shared__ float s_h[HID];
  __shared__ float s_g[G4];
  __shared__ int   s_fz;

  // W_hh row g -> 32 float4 = 128 VGPRs, pinned via opaque asm (no remat)
  float4 wv[32];
  {
    const float4* wr = (const float4*)(W_hh + (size_t)g * HID);
    #pragma unroll
    for (int u = 0; u < 32; ++u) {
      float4 t = wr[u];
      asm volatile("" : "+v"(t.x), "+v"(t.y), "+v"(t.z), "+v"(t.w));
      wv[u] = t;
    }
  }
  const float bias = b_ih[g] + b_hh[g];
  const float wih  = W_ih[g];

  if (g == 0) s_fz = TSEQ;
  __syncthreads();
  if (g < TSEQ) {
    float v = x[(size_t)n * TSEQ + g];
    s_x[g] = v;
    if (v == 0.0f) atomicMin(&s_fz, g);   // first zero index
  }
  if (g < HID) s_h[g] = 0.0f;
  __syncthreads();

  // reference: maxes==0 -> len=T, else first_zero+1
  const int fz  = s_fz;
  const int len = (fz == 0 || fz >= TSEQ) ? TSEQ : (fz + 1);

  const int gtype = g >> 7;   // 0:i 1:f 2:g(tanh) 3:o  (wave-uniform)
  const int u128  = g & 127;  // hidden unit this thread updates (redundant x4)
  float c = 0.0f;             // cell state for unit u128 (replicated, consistent)
  float* __restrict__ hrow = hs + (size_t)n * TSEQ * HID;

  for (int t = 0; t < len; ++t) {
    // gate pre-activation: bias + wih*x_t + <h, W_hh[g,:]>
    float a0 = fmaf(wih, s_x[t], bias);
    float a1 = 0.f, a2 = 0.f, a3 = 0.f;   // 4 accumulators: break dep chain
    const float4* h4 = (const float4*)s_h;
    #pragma unroll
    for (int u = 0; u < 32; ++u) {
      float4 hv = h4[u];                  // same-address broadcast read
      a0 = fmaf(hv.x, wv[u].x, a0);
      a1 = fmaf(hv.y, wv[u].y, a1);
      a2 = fmaf(hv.z, wv[u].z, a2);
      a3 = fmaf(hv.w, wv[u].w, a3);
    }
    float a = (a0 + a1) + (a2 + a3);
    float act = (gtype == 2) ? fast_tanh(a) : fast_sigmoid(a);
    s_g[g] = act;
    __syncthreads();
    // c/h update on ALL threads (redundant x4) so the serial tail spreads
    // over 8 waves instead of 2; only g<128 stores.
    {
      float I = s_g[u128], F = s_g[HID+u128], Gg = s_g[2*HID+u128], O = s_g[3*HID+u128];
      c = fmaf(F, c, I * Gg);
      float h = O * fast_tanh(c);
      if (g < HID) {
        s_h[g] = h;
        hrow[(size_t)t * HID + g] = h;    // coalesced 512B store
      }
    }
    __syncthreads();
  }
  // zero masked tail (t >= len) so GEMM1 can run dense over full K
  for (int t = len; t < TSEQ; ++t)
    if (g < HID) hrow[(size_t)t * HID + g] = 0.0f;
}

// ---------------------------------------------------------------------------
// GEMM1: part[ks][n][i] = sum_{k in ks-slice} hs[n][k] * W1[i][k]
// ---------------------------------------------------------------------------
__global__ __launch_bounds__(256) void gemm1_kernel(
    const float* __restrict__ hs,    // [NSEQ, KTOT]
    const float* __restrict__ W1,    // [64, KTOT]
    float* __restrict__ part)        // [KSPLIT, NSEQ, 64]
{
  const int blk   = blockIdx.x;            // 0 .. 80*KSPLIT-1
  const int ntile = blk / KSPLIT;
  const int ks    = blk % KSPLIT;
  const int n0    = ntile * NT;
  const int kbase = ks * KPB;
  const int tid = threadIdx.x;
  const int ig  = tid & 31;                // i-pair group
  const int i0  = ig * 2;
  const int p   = tid >> 5;                // k4 phase 0..7

  __shared__ float s_hs[NT][KCH];          // 8 KB
  __shared__ float s_red[8][NT][64];       // 32 KB

  float acc[2][NT];
  #pragma unroll
  for (int ii = 0; ii < 2; ++ii)
    #pragma unroll
    for (int r = 0; r < NT; ++r) acc[ii][r] = 0.f;

  const float* w1a = W1 + (size_t)i0 * KTOT;
  const float* w1b = W1 + (size_t)(i0 + 1) * KTOT;

  for (int kc = 0; kc < KPB; kc += KCH) {
    const int k0 = kbase + kc;
    __syncthreads();
    #pragma unroll
    for (int u = 0; u < 2; ++u) {          // stage 16x128 floats, coalesced
      int v  = tid + u * 256;
      int r  = v >> 5;
      int cc = v & 31;
      ((float4*)&s_hs[r][0])[cc] =
          *(const float4*)(hs + (size_t)(n0 + r) * KTOT + k0 + cc * 4);
    }
    __syncthreads();
    #pragma unroll
    for (int u = 0; u < 4; ++u) {
      int k4 = p + u * 8;
      float4 wv0 = *(const float4*)(w1a + k0 + k4 * 4);
      float4 wv1 = *(const float4*)(w1b + k0 + k4 * 4);
      #pragma unroll
      for (int r = 0; r < NT; ++r) {
        float4 hv = ((const float4*)&s_hs[r][0])[k4];  // broadcast per phase
        acc[0][r] = fmaf(wv0.x, hv.x, acc[0][r]);
        acc[0][r] = fmaf(wv0.y, hv.y, acc[0][r]);
        acc[0][r] = fmaf(wv0.z, hv.z, acc[0][r]);
        acc[0][r] = fmaf(wv0.w, hv.w, acc[0][r]);
        acc[1][r] = fmaf(wv1.x, hv.x, acc[1][r]);
        acc[1][r] = fmaf(wv1.y, hv.y, acc[1][r]);
        acc[1][r] = fmaf(wv1.z, hv.z, acc[1][r]);
        acc[1][r] = fmaf(wv1.w, hv.w, acc[1][r]);
      }
    }
  }
  __syncthreads();
  #pragma unroll
  for (int ii = 0; ii < 2; ++ii)
    #pragma unroll
    for (int r = 0; r < NT; ++r)
      s_red[p][r][i0 + ii] = acc[ii][r];
  __syncthreads();
  #pragma unroll
  for (int u = 0; u < 4; ++u) {            // 1024 outputs / 256 threads
    int idx = tid + u * 256;
    int r = idx >> 6;
    int i = idx & 63;
    float v = 0.f;
    #pragma unroll
    for (int q = 0; q < 8; ++q) v += s_red[q][r][i];
    part[((size_t)ks * NSEQ + (n0 + r)) * 64 + i] = v;
  }
}

// ---------------------------------------------------------------------------
// GEMM2: out[b][m] = b2[m] + sum_k (b1[k&63] + sum_q part[q][b*20..][k]) * W2[m][k]
// ---------------------------------------------------------------------------
__global__ __launch_bounds__(128) void gemm2_kernel(
    const float* __restrict__ part,  // [KSPLIT, NSEQ, 64]
    const float* __restrict__ b1,    // [64]
    const float* __restrict__ W2,    // [2, 1280]
    const float* __restrict__ b2,    // [2]
    float* __restrict__ out)         // [64, 2]
{
  const int tid = threadIdx.x;
  const int b = tid >> 1;
  const int m = tid & 1;
  const float4* w4  = (const float4*)(W2 + (size_t)m * 1280);
  const float4* b14 = (const float4*)b1;
  float4 acc4 = {0.f, 0.f, 0.f, 0.f};
  for (int k4 = 0; k4 < 320; ++k4) {
    float4 f = b14[k4 & 15];
    #pragma unroll
    for (int q = 0; q < KSPLIT; ++q) {
      float4 pv = *(const float4*)(part + ((size_t)q * NSEQ + b * 20) * 64 + k4 * 4);
      f.x += pv.x; f.y += pv.y; f.z += pv.z; f.w += pv.w;
    }
    float4 wv = w4[k4];
    acc4.x = fmaf(f.x, wv.x, acc4.x);
    acc4.y = fmaf(f.y, wv.y, acc4.y);
    acc4.z = fmaf(f.z, wv.z, acc4.z);
    acc4.w = fmaf(f.w, wv.w, acc4.w);
  }
  out[b * 2 + m] = ((acc4.x + acc4.y) + (acc4.z + acc4.w)) + b2[m];
}

// ---------------------------------------------------------------------------
extern "C" void kernel_launch(void* const* d_in, const int* in_sizes, int n_in,
                              void* d_out, int out_size, void* d_ws, size_t ws_size,
                              hipStream_t stream) {
  const float* x    = (const float*)d_in[0];
  // d_in[1] = metadata: unused by the reference
  const float* W_ih = (const float*)d_in[2];
  const float* W_hh = (const float*)d_in[3];
  const float* b_ih = (const float*)d_in[4];
  const float* b_hh = (const float*)d_in[5];
  const float* W1   = (const float*)d_in[6];
  const float* b1   = (const float*)d_in[7];
  const float* W2   = (const float*)d_in[8];
  const float* b2   = (const float*)d_in[9];
  float* out = (float*)d_out;

  // workspace layout: hs [1280*28672] f32 (146.8 MB) + part [8*1280*64] f32 (2.6 MB)
  float* hs   = (float*)d_ws;
  float* part = hs + (size_t)NSEQ * KTOT;

  lstm_kernel<<<NSEQ, 512, 0, stream>>>(x, W_ih, W_hh, b_ih, b_hh, hs);
  gemm1_kernel<<<(NSEQ / NT) * KSPLIT, 256, 0, stream>>>(hs, W1, part);
  gemm2_kernel<<<1, 128, 0, stream>>>(part, b1, W2, b2, out);
}

// Round 4
// 628.160 us; speedup vs baseline: 1.9967x; 1.9967x over previous
//
#include <hip/hip_runtime.h>
#include <cstdint>

// Problem constants (from reference)
#define TSEQ 224
#define HID 128
#define NSEQ 1280           // BATCHES*SUB = 64*20
#define KTOT (TSEQ*HID)     // 28672
#define NB 16               // sequences per LSTM block
#define NT 16               // sequences per GEMM1 block
#define KSPLIT 8            // K-split for GEMM1
#define KCH 128             // K staging chunk
#define KPB (KTOT/KSPLIT)   // 3584

typedef short bf16x8 __attribute__((ext_vector_type(8)));
typedef float f32x4  __attribute__((ext_vector_type(4)));

__device__ __forceinline__ float fast_sigmoid(float a) {
  float e = __expf(-a);
  return __builtin_amdgcn_rcpf(1.0f + e);
}
__device__ __forceinline__ float fast_tanh(float a) {
  float e = __expf(-2.0f * a);
  return fmaf(2.0f, __builtin_amdgcn_rcpf(1.0f + e), -1.0f);
}

// Truncate-split packing: two fp32 -> one uint holding 2 bf16 (hi parts),
// and residual lo parts. Truncation keeps residual exactly representable.
__device__ __forceinline__ void split2(float a, float b,
                                       unsigned int& hi, unsigned int& lo) {
  unsigned int ua = __float_as_uint(a), ub = __float_as_uint(b);
  unsigned int ha = ua & 0xFFFF0000u,  hb = ub & 0xFFFF0000u;
  float ra = a - __uint_as_float(ha);
  float rb = b - __uint_as_float(hb);
  hi = (ha >> 16) | hb;
  lo = (__float_as_uint(ra) >> 16) | (__float_as_uint(rb) & 0xFFFF0000u);
}

// ---------------------------------------------------------------------------
// MFMA LSTM. 80 blocks x 512 threads; each block owns NB=16 sequences.
// gates[512x16] = W'[512x128] @ h[128x16] via 16x16x32 bf16 MFMA, split-bf16
// 3-pass (Whi*hhi + Wlo*hhi + Whi*hlo) for ~fp32 accuracy. W' rows permuted so
// that within each 16-row D tile, row m = (unit q = m>>2)*4 + gate(m&3): then
// lane l of tile mt holds gates i,f,g,o of unit u=MT*4+(l>>4), seq n=l&15 in
// its 4 acc regs -> c/h update fully in-lane. A-fragments resident in VGPRs
// (built via load+cvt chains, occupancy pinned by amdgpu_waves_per_eu(2,2)).
// Per-step cross-thread traffic: h repack (2KB fp32 + 4KB bf16) only.
// ---------------------------------------------------------------------------
__attribute__((amdgpu_waves_per_eu(2, 2)))
__global__ __launch_bounds__(512) void lstm_mfma(
    const float* __restrict__ x,      // [NSEQ, TSEQ]
    const float* __restrict__ W_ih,   // [512, 1]
    const float* __restrict__ W_hh,   // [512, 128]
    const float* __restrict__ b_ih,   // [512]
    const float* __restrict__ b_hh,   // [512]
    float* __restrict__ hs)           // [NSEQ, TSEQ, HID]
{
  const int tid = threadIdx.x;
  const int w   = tid >> 6;          // wave 0..7
  const int l   = tid & 63;          // lane
  const int lm  = l & 15;            // seq col n (D/B); A-frag row
  const int lq  = l >> 4;            // quad
  const int n0  = blockIdx.x * NB;

  __shared__ float s_x[NB][228];                         // padded: bank spread
  __shared__ int   s_fz[NB];
  __shared__ int   s_len[NB];
  __shared__ int   s_maxlen;
  __shared__ __align__(16) unsigned short s_hhi[4][64][8];  // B-frags hi [kt][lane][j]
  __shared__ __align__(16) unsigned short s_hlo[4][64][8];  // B-frags lo
  __shared__ float s_hT[HID][17];                        // h fp32 [unit][seq]

  // ---- stage x (coalesced: 32 threads per sequence), find first zero
  if (tid < NB) s_fz[tid] = TSEQ;
  __syncthreads();
  {
    const int n = tid >> 5, j = tid & 31;
    const float* xrow = x + (size_t)(n0 + n) * TSEQ;
    #pragma unroll
    for (int i = 0; i < 7; ++i) {
      int t = j + 32 * i;
      float v = xrow[t];
      s_x[n][t] = v;
      if (v == 0.0f) atomicMin(&s_fz[n], t);
    }
  }
  // zero-init B-frag buffers (h0 = 0)
  {
    unsigned int* ph = (unsigned int*)&s_hhi[0][0][0];
    unsigned int* pl = (unsigned int*)&s_hlo[0][0][0];
    ph[tid] = 0; ph[tid + 512] = 0;
    pl[tid] = 0; pl[tid + 512] = 0;
  }
  __syncthreads();
  if (tid < NB) {
    int fz = s_fz[tid];
    s_len[tid] = (fz == 0 || fz >= TSEQ) ? TSEQ : fz + 1;  // reference quirk
  }
  __syncthreads();
  if (tid == 0) {
    int m = 0;
    for (int n = 0; n < NB; ++n) m = max(m, s_len[n]);
    s_maxlen = m;
  }
  __syncthreads();
  const int maxlen = s_maxlen;

  // ---- load A-fragments (W' permuted, split hi/lo) + per-lane constants
  bf16x8 whi[4][4], wlo[4][4];       // [mt][kt] : 128 VGPRs total
  #pragma unroll
  for (int mt = 0; mt < 4; ++mt) {
    const int MT   = w * 4 + mt;
    const int orow = (lm & 3) * 128 + MT * 4 + (lm >> 2);  // W' row permutation
    const float* wr = W_hh + (size_t)orow * HID;
    #pragma unroll
    for (int kt = 0; kt < 4; ++kt) {
      const int k0 = kt * 32 + lq * 8;
      union { bf16x8 v; unsigned int u[4]; } hi, lo;
      #pragma unroll
      for (int p = 0; p < 4; ++p)
        split2(wr[k0 + 2 * p], wr[k0 + 2 * p + 1], hi.u[p], lo.u[p]);
      whi[mt][kt] = hi.v;
      wlo[mt][kt] = lo.v;
    }
  }
  float bias_[4][4], wih_[4][4], c_[4];
  #pragma unroll
  for (int mt = 0; mt < 4; ++mt) {
    const int u_ = (w * 4 + mt) * 4 + lq;
    c_[mt] = 0.0f;
    #pragma unroll
    for (int r = 0; r < 4; ++r) {
      const int g = r * 128 + u_;       // r: 0=i 1=f 2=g~ 3=o
      bias_[mt][r] = b_ih[g] + b_hh[g];
      wih_[mt][r]  = W_ih[g];
    }
  }
  // role constants for phase 2
  const int rp_kt = tid >> 6;                 // repack (tid<256)
  const int rp_l  = tid & 63;
  const int rp_n  = rp_l & 15, rp_q = rp_l >> 4;
  const int st_t2 = tid - 256;                // store (tid>=256)
  const int st_n  = (st_t2 >> 4) & 15;
  const int st_u8 = (st_t2 & 15) * 8;
  const int st_len = s_len[st_n];

  for (int t = 0; t < maxlen; ++t) {
    // B-fragments for this step (written by repack of previous step / init)
    bf16x8 bh[4], bl[4];
    #pragma unroll
    for (int kt = 0; kt < 4; ++kt) {
      bh[kt] = *(const bf16x8*)&s_hhi[kt][l][0];
      bl[kt] = *(const bf16x8*)&s_hlo[kt][l][0];
    }
    const float xv = s_x[lm][t];
    f32x4 acc[4];
    #pragma unroll
    for (int mt = 0; mt < 4; ++mt)
      #pragma unroll
      for (int r = 0; r < 4; ++r)
        acc[mt][r] = fmaf(wih_[mt][r], xv, bias_[mt][r]);
    #pragma unroll
    for (int kt = 0; kt < 4; ++kt)
      #pragma unroll
      for (int mt = 0; mt < 4; ++mt)
        acc[mt] = __builtin_amdgcn_mfma_f32_16x16x32_bf16(whi[mt][kt], bh[kt], acc[mt], 0, 0, 0);
    #pragma unroll
    for (int kt = 0; kt < 4; ++kt)
      #pragma unroll
      for (int mt = 0; mt < 4; ++mt)
        acc[mt] = __builtin_amdgcn_mfma_f32_16x16x32_bf16(wlo[mt][kt], bh[kt], acc[mt], 0, 0, 0);
    #pragma unroll
    for (int kt = 0; kt < 4; ++kt)
      #pragma unroll
      for (int mt = 0; mt < 4; ++mt)
        acc[mt] = __builtin_amdgcn_mfma_f32_16x16x32_bf16(whi[mt][kt], bl[kt], acc[mt], 0, 0, 0);
    // in-lane LSTM update: lane owns unit u = MT*4+lq, seq lm; regs = i,f,g~,o
    #pragma unroll
    for (int mt = 0; mt < 4; ++mt) {
      float i_ = fast_sigmoid(acc[mt][0]);
      float f_ = fast_sigmoid(acc[mt][1]);
      float g_ = fast_tanh(acc[mt][2]);
      float o_ = fast_sigmoid(acc[mt][3]);
      c_[mt] = fmaf(f_, c_[mt], i_ * g_);
      float h_ = o_ * fast_tanh(c_[mt]);
      s_hT[(w * 4 + mt) * 4 + lq][lm] = h_;
    }
    __syncthreads();
    // phase 2: repack h -> B-frag layout (waves 0-3), store hs (waves 4-7)
    if (tid < 256) {
      union { bf16x8 v; unsigned int u[4]; } hi, lo;
      #pragma unroll
      for (int p = 0; p < 4; ++p) {
        float a = s_hT[rp_kt * 32 + rp_q * 8 + 2 * p][rp_n];
        float b = s_hT[rp_kt * 32 + rp_q * 8 + 2 * p + 1][rp_n];
        split2(a, b, hi.u[p], lo.u[p]);
      }
      *(bf16x8*)&s_hhi[rp_kt][rp_l][0] = hi.v;
      *(bf16x8*)&s_hlo[rp_kt][rp_l][0] = lo.v;
    } else {
      const float keep = (t < st_len) ? 1.0f : 0.0f;
      float v[8];
      #pragma unroll
      for (int j = 0; j < 8; ++j) v[j] = s_hT[st_u8 + j][st_n] * keep;
      float* dst = hs + ((size_t)(n0 + st_n) * TSEQ + t) * HID + st_u8;
      *(float4*)dst       = make_float4(v[0], v[1], v[2], v[3]);
      *(float4*)(dst + 4) = make_float4(v[4], v[5], v[6], v[7]);
    }
    __syncthreads();
  }
  // zero tail t in [maxlen, TSEQ) for all 16 seqs
  {
    const int n = tid >> 5, u4 = (tid & 31) * 4;
    const float4 z = make_float4(0.f, 0.f, 0.f, 0.f);
    for (int t = maxlen; t < TSEQ; ++t)
      *(float4*)(hs + ((size_t)(n0 + n) * TSEQ + t) * HID + u4) = z;
  }
}

// ---------------------------------------------------------------------------
// GEMM1: part[ks][n][i] = sum_{k in ks-slice} hs[n][k] * W1[i][k]  (unchanged)
// ---------------------------------------------------------------------------
__global__ __launch_bounds__(256) void gemm1_kernel(
    const float* __restrict__ hs,    // [NSEQ, KTOT]
    const float* __restrict__ W1,    // [64, KTOT]
    float* __restrict__ part)        // [KSPLIT, NSEQ, 64]
{
  const int blk   = blockIdx.x;            // 0 .. 80*KSPLIT-1
  const int ntile = blk / KSPLIT;
  const int ks    = blk % KSPLIT;
  const int n0    = ntile * NT;
  const int kbase = ks * KPB;
  const int tid = threadIdx.x;
  const int ig  = tid & 31;                // i-pair group
  const int i0  = ig * 2;
  const int p   = tid >> 5;                // k4 phase 0..7

  __shared__ float s_hs[NT][KCH];          // 8 KB
  __shared__ float s_red[8][NT][64];       // 32 KB

  float acc[2][NT];
  #pragma unroll
  for (int ii = 0; ii < 2; ++ii)
    #pragma unroll
    for (int r = 0; r < NT; ++r) acc[ii][r] = 0.f;

  const float* w1a = W1 + (size_t)i0 * KTOT;
  const float* w1b = W1 + (size_t)(i0 + 1) * KTOT;

  for (int kc = 0; kc < KPB; kc += KCH) {
    const int k0 = kbase + kc;
    __syncthreads();
    #pragma unroll
    for (int u = 0; u < 2; ++u) {          // stage 16x128 floats, coalesced
      int v  = tid + u * 256;
      int r  = v >> 5;
      int cc = v & 31;
      ((float4*)&s_hs[r][0])[cc] =
          *(const float4*)(hs + (size_t)(n0 + r) * KTOT + k0 + cc * 4);
    }
    __syncthreads();
    #pragma unroll
    for (int u = 0; u < 4; ++u) {
      int k4 = p + u * 8;
      float4 wv0 = *(const float4*)(w1a + k0 + k4 * 4);
      float4 wv1 = *(const float4*)(w1b + k0 + k4 * 4);
      #pragma unroll
      for (int r = 0; r < NT; ++r) {
        float4 hv = ((const float4*)&s_hs[r][0])[k4];  // broadcast per phase
        acc[0][r] = fmaf(wv0.x, hv.x, acc[0][r]);
        acc[0][r] = fmaf(wv0.y, hv.y, acc[0][r]);
        acc[0][r] = fmaf(wv0.z, hv.z, acc[0][r]);
        acc[0][r] = fmaf(wv0.w, hv.w, acc[0][r]);
        acc[1][r] = fmaf(wv1.x, hv.x, acc[1][r]);
        acc[1][r] = fmaf(wv1.y, hv.y, acc[1][r]);
        acc[1][r] = fmaf(wv1.z, hv.z, acc[1][r]);
        acc[1][r] = fmaf(wv1.w, hv.w, acc[1][r]);
      }
    }
  }
  __syncthreads();
  #pragma unroll
  for (int ii = 0; ii < 2; ++ii)
    #pragma unroll
    for (int r = 0; r < NT; ++r)
      s_red[p][r][i0 + ii] = acc[ii][r];
  __syncthreads();
  #pragma unroll
  for (int u = 0; u < 4; ++u) {            // 1024 outputs / 256 threads
    int idx = tid + u * 256;
    int r = idx >> 6;
    int i = idx & 63;
    float v = 0.f;
    #pragma unroll
    for (int q = 0; q < 8; ++q) v += s_red[q][r][i];
    part[((size_t)ks * NSEQ + (n0 + r)) * 64 + i] = v;
  }
}

// ---------------------------------------------------------------------------
// GEMM2 (unchanged)
// ---------------------------------------------------------------------------
__global__ __launch_bounds__(128) void gemm2_kernel(
    const float* __restrict__ part,  // [KSPLIT, NSEQ, 64]
    const float* __restrict__ b1,    // [64]
    const float* __restrict__ W2,    // [2, 1280]
    const float* __restrict__ b2,    // [2]
    float* __restrict__ out)         // [64, 2]
{
  const int tid = threadIdx.x;
  const int b = tid >> 1;
  const int m = tid & 1;
  const float4* w4  = (const float4*)(W2 + (size_t)m * 1280);
  const float4* b14 = (const float4*)b1;
  float4 acc4 = {0.f, 0.f, 0.f, 0.f};
  for (int k4 = 0; k4 < 320; ++k4) {
    float4 f = b14[k4 & 15];
    #pragma unroll
    for (int q = 0; q < KSPLIT; ++q) {
      float4 pv = *(const float4*)(part + ((size_t)q * NSEQ + b * 20) * 64 + k4 * 4);
      f.x += pv.x; f.y += pv.y; f.z += pv.z; f.w += pv.w;
    }
    float4 wv = w4[k4];
    acc4.x = fmaf(f.x, wv.x, acc4.x);
    acc4.y = fmaf(f.y, wv.y, acc4.y);
    acc4.z = fmaf(f.z, wv.z, acc4.z);
    acc4.w = fmaf(f.w, wv.w, acc4.w);
  }
  out[b * 2 + m] = ((acc4.x + acc4.y) + (acc4.z + acc4.w)) + b2[m];
}

// ---------------------------------------------------------------------------
extern "C" void kernel_launch(void* const* d_in, const int* in_sizes, int n_in,
                              void* d_out, int out_size, void* d_ws, size_t ws_size,
                              hipStream_t stream) {
  const float* x    = (const float*)d_in[0];
  // d_in[1] = metadata: unused by the reference
  const float* W_ih = (const float*)d_in[2];
  const float* W_hh = (const float*)d_in[3];
  const float* b_ih = (const float*)d_in[4];
  const float* b_hh = (const float*)d_in[5];
  const float* W1   = (const float*)d_in[6];
  const float* b1   = (const float*)d_in[7];
  const float* W2   = (const float*)d_in[8];
  const float* b2   = (const float*)d_in[9];
  float* out = (float*)d_out;

  // workspace layout: hs [1280*28672] f32 (146.8 MB) + part [8*1280*64] f32 (2.6 MB)
  float* hs   = (float*)d_ws;
  float* part = hs + (size_t)NSEQ * KTOT;

  lstm_mfma<<<NSEQ / NB, 512, 0, stream>>>(x, W_ih, W_hh, b_ih, b_hh, hs);
  gemm1_kernel<<<(NSEQ / NT) * KSPLIT, 256, 0, stream>>>(hs, W1, part);
  gemm2_kernel<<<1, 128, 0, stream>>>(part, b1, W2, b2, out);
}